// Round 8
// baseline (5327.036 us; speedup 1.0000x reference)
//
#include <hip/hip_runtime.h>
#include <hip/hip_bf16.h>

// BiLSTM-CRF forward: B=32, T=512, E=512, H=256 (per dir), 4H=1024, K=12
// Inputs: fp32 (+ int32 sentence). Outputs fp32:
//   [0,1024)      path_score [32][32]
//   [1024,17408)  best_path  [32][512] (tags as fp32)
// R8: flagless exchange — h words are self-announcing 64-bit (stamp|data)
// agent-scope atomics; consumers poll their own data. One LLC hop per step.

typedef __attribute__((ext_vector_type(8))) __bf16 bf16x8;
typedef __attribute__((ext_vector_type(8))) unsigned short u16x8;
typedef __attribute__((ext_vector_type(4))) float  f32x4;

#define MFMA16(a, b, c) __builtin_amdgcn_mfma_f32_16x16x32_bf16((a), (b), (c), 0, 0, 0)

__device__ __forceinline__ float sigm(float x) { return 1.0f / (1.0f + __expf(-x)); }
__device__ __forceinline__ float tanh_f(float x) {
  x = fminf(fmaxf(x, -15.0f), 15.0f);
  float e = __expf(2.0f * x);
  return (e - 1.0f) / (e + 1.0f);
}

__device__ __forceinline__ void split8(const float* v, bf16x8& hi, bf16x8& lo) {
#pragma unroll
  for (int j = 0; j < 8; j++) {
    __bf16 h = (__bf16)v[j];
    hi[j] = h;
    lo[j] = (__bf16)(v[j] - (float)h);
  }
}

// ---------------------------------------------------------------------------
// Kernel 1: xg[m=(b,t)][n=(dir,gate,unit)] = embed[sent[m]].w_ih[n] + bias[n]
// M=16384, N=2048, K=512. 128x128 tile/WG, 4 waves 2x2, 3-term hi/lo MFMA.
// ---------------------------------------------------------------------------
__global__ __launch_bounds__(256) void xg_gemm(
    const int* __restrict__ sent, const float* __restrict__ embed,
    const float* __restrict__ wih_f, const float* __restrict__ wih_b,
    const float* __restrict__ bias_f, const float* __restrict__ bias_b,
    float* __restrict__ xg)
{
  __shared__ __bf16 Ah[128][40], Al[128][40];  // 32 k + 8 pad
  __shared__ __bf16 Bh[128][40], Bl[128][40];
  __shared__ int toks[128];
  const int tid = threadIdx.x;
  const int m0 = blockIdx.x * 128, n0 = blockIdx.y * 128;
  if (tid < 128) toks[tid] = sent[m0 + tid];
  const int wave = tid >> 6, lane = tid & 63, q = lane >> 4, c = lane & 15;
  const int wy = wave >> 1, wx = wave & 1;
  f32x4 acc[4][4];
  for (int mt = 0; mt < 4; mt++)
    for (int nt = 0; nt < 4; nt++)
      acc[mt][nt] = f32x4{0.0f, 0.0f, 0.0f, 0.0f};
  __syncthreads();

  for (int k0 = 0; k0 < 512; k0 += 32) {
#pragma unroll
    for (int i = 0; i < 2; i++) {
      int ch = tid + (i << 8);
      int r = ch >> 2, kc = ch & 3;
      float tmp[8];
      const float* asrc = embed + (size_t)toks[r] * 512 + k0 + kc * 8;
#pragma unroll
      for (int j = 0; j < 8; j++) tmp[j] = asrc[j];
      bf16x8 hi, lo;
      split8(tmp, hi, lo);
      *(bf16x8*)&Ah[r][kc * 8] = hi;
      *(bf16x8*)&Al[r][kc * 8] = lo;
      int n = n0 + r;
      const float* wsrc = (n < 1024) ? (wih_f + (size_t)n * 512)
                                     : (wih_b + (size_t)(n - 1024) * 512);
#pragma unroll
      for (int j = 0; j < 8; j++) tmp[j] = wsrc[k0 + kc * 8 + j];
      split8(tmp, hi, lo);
      *(bf16x8*)&Bh[r][kc * 8] = hi;
      *(bf16x8*)&Bl[r][kc * 8] = lo;
    }
    __syncthreads();
    bf16x8 ah[4], al[4], bh[4], bl[4];
#pragma unroll
    for (int t4 = 0; t4 < 4; t4++) {
      int ar = wy * 64 + t4 * 16 + c, br = wx * 64 + t4 * 16 + c;
      ah[t4] = *(const bf16x8*)&Ah[ar][q * 8];
      al[t4] = *(const bf16x8*)&Al[ar][q * 8];
      bh[t4] = *(const bf16x8*)&Bh[br][q * 8];
      bl[t4] = *(const bf16x8*)&Bl[br][q * 8];
    }
#pragma unroll
    for (int mt = 0; mt < 4; mt++)
#pragma unroll
      for (int nt = 0; nt < 4; nt++) {
        acc[mt][nt] = MFMA16(ah[mt], bh[nt], acc[mt][nt]);
        acc[mt][nt] = MFMA16(al[mt], bh[nt], acc[mt][nt]);
        acc[mt][nt] = MFMA16(ah[mt], bl[nt], acc[mt][nt]);
      }
    __syncthreads();
  }

#pragma unroll
  for (int nt = 0; nt < 4; nt++) {
    int n = n0 + wx * 64 + nt * 16 + c;
    float bval = (n < 1024) ? bias_f[n] : bias_b[n - 1024];
#pragma unroll
    for (int mt = 0; mt < 4; mt++) {
      int mbase = m0 + wy * 64 + mt * 16 + q * 4;
#pragma unroll
      for (int reg = 0; reg < 4; reg++)
        xg[(size_t)(mbase + reg) * 2048 + n] = acc[mt][nt][reg] + bval;
    }
  }
}

// ---------------------------------------------------------------------------
// Kernel 2: both LSTM recurrences. 8 blocks: blk = d*4 + hs.
// WG owns 64 hidden units (256 gate rows) for ALL 32 batches; w_hh slice
// (hi/lo bf16 of fp32) persistent in VGPRs/AGPRs as MFMA B-frags.
// h exchange: hx[parity][dir][b][u] 64-bit words (stamp<<32 | hi<<16 | lo),
// agent-scope relaxed atomics. Consumers poll their own words until
// stamp == s. No flags, no fences, no producer-side drain on critical path.
// ---------------------------------------------------------------------------
__global__ __launch_bounds__(256, 1) void lstm_rec(
    const float* __restrict__ xg,
    const float* __restrict__ whh_f, const float* __restrict__ whh_b,
    const float* __restrict__ h0, const float* __restrict__ c0,
    float* __restrict__ h_seq,     // [32][512][512]: cols 0-255 fwd, 256-511 bwd
    unsigned long long* __restrict__ hx) // [2][2][32][256] stamped words
{
  const int blk = blockIdx.x;
  const int d = blk >> 2, hs = blk & 3;
  const int tid = threadIdx.x;
  const int wave = tid >> 6, lane = tid & 63, q = lane >> 4, c = lane & 15;
  const float* __restrict__ whh = d ? whh_b : whh_f;

  __shared__ __bf16 hfrag[2][16][512];   // [hi/lo][mt*8+ks][xor-swizzled frag]

  bf16x8 wfh[4][8], wfl[4][8];
#pragma unroll
  for (int g = 0; g < 4; g++) {
    int row = g * 256 + hs * 64 + wave * 16 + c;   // w_hh row (gate-major)
    const float* wr = whh + (size_t)row * 256;
#pragma unroll
    for (int ks = 0; ks < 8; ks++) {
      float tmp[8];
#pragma unroll
      for (int j = 0; j < 8; j++) tmp[j] = wr[ks * 32 + q * 8 + j];
      split8(tmp, wfh[g][ks], wfl[g][ks]);
    }
  }
  const int ug = hs * 64 + wave * 16 + c;
  float cst[2][4];
#pragma unroll
  for (int mt = 0; mt < 2; mt++)
#pragma unroll
    for (int reg = 0; reg < 4; reg++)
      cst[mt][reg] = c0[d * 8192 + (mt * 16 + q * 4 + reg) * 256 + ug];

  const int sb = tid >> 3;            // staging: batch row
  const int kc4 = (tid & 7) * 4;      // staging: first 8-elem chunk

  for (int s = 0; s < 512; s++) {
    const int t_seq = d ? (511 - s) : s;

    // prefetch xg for this step (poll-independent): loads fly during the wait
    float xv[2][4][4];
#pragma unroll
    for (int mt = 0; mt < 2; mt++)
#pragma unroll
      for (int reg = 0; reg < 4; reg++) {
        int b = mt * 16 + q * 4 + reg;
        const float* xr = xg + ((size_t)(b * 512 + t_seq) << 11) + (d << 10) + ug;
#pragma unroll
        for (int g = 0; g < 4; g++)
          xv[mt][g][reg] = xr[g << 8];
      }

    unsigned long long v[32];
    if (s > 0) {
      const unsigned long long* hb =
          hx + ((size_t)(((s & 1) * 2 + d) * 32 + sb)) * 256 + kc4 * 8;
      const unsigned int want = (unsigned int)s;
#pragma unroll
      for (int i = 0; i < 32; i++)
        v[i] = __hip_atomic_load(hb + i, __ATOMIC_RELAXED,
                                 __HIP_MEMORY_SCOPE_AGENT);
      while (true) {
        bool all = true;
#pragma unroll
        for (int i = 0; i < 32; i++)
          all &= ((unsigned int)(v[i] >> 32) == want);
        if (all) break;
        __builtin_amdgcn_s_sleep(1);
#pragma unroll
        for (int i = 0; i < 32; i++)
          if ((unsigned int)(v[i] >> 32) != want)
            v[i] = __hip_atomic_load(hb + i, __ATOMIC_RELAXED,
                                     __HIP_MEMORY_SCOPE_AGENT);
      }
    }

    __syncthreads();   // prev iter's hfrag readers done before overwrite

    if (s == 0) {
#pragma unroll
      for (int i = 0; i < 4; i++) {
        int kc = kc4 + i;
        float tmp[8];
        const float* src = h0 + d * 8192 + sb * 256 + kc * 8;
#pragma unroll
        for (int j = 0; j < 8; j++) tmp[j] = src[j];
        bf16x8 vhi, vlo;
        split8(tmp, vhi, vlo);
        int fid = ((sb >> 4) << 3) + (kc >> 2);
        int cid = ((kc & 3) << 4) + (sb & 15);
        int pos = cid ^ (fid & 7);
        *(bf16x8*)&hfrag[0][fid][pos * 8] = vhi;
        *(bf16x8*)&hfrag[1][fid][pos * 8] = vlo;
      }
    } else {
#pragma unroll
      for (int i = 0; i < 4; i++) {
        int kc = kc4 + i;
        u16x8 vhi, vlo;
#pragma unroll
        for (int j = 0; j < 8; j++) {
          unsigned int pk = (unsigned int)v[i * 8 + j];
          vhi[j] = (unsigned short)(pk >> 16);
          vlo[j] = (unsigned short)(pk & 0xffffu);
        }
        int fid = ((sb >> 4) << 3) + (kc >> 2);
        int cid = ((kc & 3) << 4) + (sb & 15);
        int pos = cid ^ (fid & 7);
        *(u16x8*)&hfrag[0][fid][pos * 8] = vhi;
        *(u16x8*)&hfrag[1][fid][pos * 8] = vlo;
      }
    }

    f32x4 acc[2][4];
#pragma unroll
    for (int mt = 0; mt < 2; mt++)
#pragma unroll
      for (int g = 0; g < 4; g++)
#pragma unroll
        for (int reg = 0; reg < 4; reg++)
          acc[mt][g][reg] = xv[mt][g][reg];

    __syncthreads();   // hfrag staged before MFMA reads

#pragma unroll
    for (int ks = 0; ks < 8; ks++) {
      int pos = (lane ^ ks) * 8;
      bf16x8 ahi0 = *(const bf16x8*)&hfrag[0][ks][pos];
      bf16x8 ahi1 = *(const bf16x8*)&hfrag[0][8 + ks][pos];
      bf16x8 alo0 = *(const bf16x8*)&hfrag[1][ks][pos];
      bf16x8 alo1 = *(const bf16x8*)&hfrag[1][8 + ks][pos];
#pragma unroll
      for (int g = 0; g < 4; g++) {
        acc[0][g] = MFMA16(ahi0, wfh[g][ks], acc[0][g]);
        acc[1][g] = MFMA16(ahi1, wfh[g][ks], acc[1][g]);
        acc[0][g] = MFMA16(alo0, wfh[g][ks], acc[0][g]);
        acc[1][g] = MFMA16(alo1, wfh[g][ks], acc[1][g]);
        acc[0][g] = MFMA16(ahi0, wfl[g][ks], acc[0][g]);
        acc[1][g] = MFMA16(ahi1, wfl[g][ks], acc[1][g]);
      }
    }

    const unsigned long long stamp = ((unsigned long long)(s + 1)) << 32;
    const size_t slot = (size_t)((((s + 1) & 1) * 2 + d) * 32);
#pragma unroll
    for (int mt = 0; mt < 2; mt++)
#pragma unroll
      for (int reg = 0; reg < 4; reg++) {
        int b = mt * 16 + q * 4 + reg;
        float iv = sigm(acc[mt][0][reg]);
        float fg = sigm(acc[mt][1][reg]);
        float gv = tanh_f(acc[mt][2][reg]);
        float ov = sigm(acc[mt][3][reg]);
        float cn = fg * cst[mt][reg] + iv * gv;
        cst[mt][reg] = cn;
        float hn = ov * tanh_f(cn);
        h_seq[((size_t)(b * 512 + t_seq) << 9) + (d << 8) + ug] = hn;
        __bf16 hhi = (__bf16)hn;
        __bf16 hlo = (__bf16)(hn - (float)hhi);
        unsigned int pack =
            ((unsigned int)__builtin_bit_cast(unsigned short, hhi) << 16) |
            (unsigned int)__builtin_bit_cast(unsigned short, hlo);
        __hip_atomic_store(hx + (slot + b) * 256 + ug, stamp | pack,
                           __ATOMIC_RELAXED, __HIP_MEMORY_SCOPE_AGENT);
      }
  }
}

// ---------------------------------------------------------------------------
// Kernel 3: feats[m][k] = h_seq[m][:] . W_out[k][:] + b_out[k]   (fp32)
// ---------------------------------------------------------------------------
__global__ __launch_bounds__(256) void feats_k(
    const float* __restrict__ h_seq, const float* __restrict__ W_out,
    const float* __restrict__ b_out, float* __restrict__ feats)
{
  int m = blockIdx.x * 4 + (threadIdx.x >> 6);
  int lane = threadIdx.x & 63;
  const float4* hp = (const float4*)(h_seq + (size_t)m * 512 + lane * 8);
  float4 a = hp[0], b2 = hp[1];
  float h[8] = {a.x, a.y, a.z, a.w, b2.x, b2.y, b2.z, b2.w};
#pragma unroll
  for (int k = 0; k < 12; k++) {
    const float4* wp = (const float4*)(W_out + k * 512 + lane * 8);
    float4 w0 = wp[0], w1 = wp[1];
    float w[8] = {w0.x, w0.y, w0.z, w0.w, w1.x, w1.y, w1.z, w1.w};
    float p = 0.0f;
#pragma unroll
    for (int j = 0; j < 8; j++) p += h[j] * w[j];
#pragma unroll
    for (int off = 32; off > 0; off >>= 1) p += __shfl_xor(p, off);
    if (lane == 0) feats[(size_t)m * 12 + k] = p + b_out[k];
  }
}

// ---------------------------------------------------------------------------
// Kernel 4: Viterbi per batch (one wave). First-max tie-break == jnp.argmax.
// ---------------------------------------------------------------------------
__global__ __launch_bounds__(64) void viterbi_k(
    const float* __restrict__ feats, const float* __restrict__ trans,
    float* __restrict__ terminal, int* __restrict__ best,
    float* __restrict__ out_path)
{
  const int b = blockIdx.x;
  const int lane = threadIdx.x;
  __shared__ unsigned char bp[512][12];
  float trow[12];
#pragma unroll
  for (int pv = 0; pv < 12; pv++)
    trow[pv] = (lane < 12) ? trans[lane * 12 + pv] : -10000.0f;
  float fv = (lane == 10) ? 0.0f : -10000.0f;   // START = 10
  for (int t = 0; t < 512; t++) {
    float bestv = -3.4e38f;
    int arg = 0;
#pragma unroll
    for (int pv = 0; pv < 12; pv++) {
      float sc = __shfl(fv, pv) + trow[pv];
      if (sc > bestv) { bestv = sc; arg = pv; }   // strict > keeps first max
    }
    float ft = (lane < 12) ? feats[(size_t)(b * 512 + t) * 12 + lane] : 0.0f;
    if (lane < 12) {
      bp[t][lane] = (unsigned char)arg;
      fv = bestv + ft;
    }
  }
  float term = fv + ((lane < 12) ? trans[11 * 12 + lane] : 0.0f);  // STOP = 11
  if (lane < 12) terminal[b * 12 + lane] = term;
  float v = (lane < 12) ? term : -3.4e38f;
  int idx = lane;
#pragma unroll
  for (int off = 8; off > 0; off >>= 1) {
    float ov = __shfl_down(v, off);
    int oi = __shfl_down(idx, off);
    if (ov > v || (ov == v && oi < idx)) { v = ov; idx = oi; }
  }
  int bidx = __shfl(idx, 0);
  __syncthreads();
  if (lane == 0) {
    best[b] = bidx;
    int tag = bidx;
    out_path[b * 512 + 511] = (float)bidx;
    for (int t = 511; t >= 1; t--) {
      tag = bp[t][tag];
      out_path[b * 512 + t - 1] = (float)tag;
    }
  }
}

// ---------------------------------------------------------------------------
// Kernel 5: path_score[i][j] = terminal[i][best[j]]
// ---------------------------------------------------------------------------
__global__ __launch_bounds__(256) void pscore_k(
    const float* __restrict__ terminal, const int* __restrict__ best,
    float* __restrict__ out)
{
  int idx = blockIdx.x * 256 + threadIdx.x;
  if (idx < 1024) {
    int i = idx >> 5, j = idx & 31;
    out[idx] = terminal[i * 12 + best[j]];
  }
}

// ---------------------------------------------------------------------------
extern "C" void kernel_launch(void* const* d_in, const int* in_sizes, int n_in,
                              void* d_out, int out_size, void* d_ws, size_t ws_size,
                              hipStream_t stream)
{
  const int*   sent  = (const int*)d_in[0];
  const float* embed = (const float*)d_in[1];
  const float* wih_f = (const float*)d_in[2];
  const float* whh_f = (const float*)d_in[3];
  const float* b_f   = (const float*)d_in[4];
  const float* wih_b = (const float*)d_in[5];
  const float* whh_b = (const float*)d_in[6];
  const float* b_b   = (const float*)d_in[7];
  const float* h0    = (const float*)d_in[8];
  const float* c0    = (const float*)d_in[9];
  const float* W_out = (const float*)d_in[10];
  const float* b_out = (const float*)d_in[11];
  const float* trans = (const float*)d_in[12];

  char* ws = (char*)d_ws;
  float*              xg    = (float*)(ws);                    // 134217728 B
  float*              h_seq = (float*)(ws + 134217728);        //  33554432 B
  float*              feats = (float*)(ws + 167772160);        //    786432 B
  unsigned long long* hx    = (unsigned long long*)(ws + 168558592); // 262144 B
  float*              term  = (float*)(ws + 168820736);        //      1536 B
  int*                best  = (int*)(ws + 168822272);          //       128 B

  float* outp = (float*)d_out;

  xg_gemm<<<dim3(128, 16), 256, 0, stream>>>(sent, embed, wih_f, wih_b, b_f, b_b, xg);
  lstm_rec<<<8, 256, 0, stream>>>(xg, whh_f, whh_b, h0, c0, h_seq, hx);
  feats_k<<<4096, 256, 0, stream>>>(h_seq, W_out, b_out, feats);
  viterbi_k<<<32, 64, 0, stream>>>(feats, trans, term, best, outp + 1024);
  pscore_k<<<4, 256, 0, stream>>>(term, best, outp);
}